// Round 4
// baseline (294.551 us; speedup 1.0000x reference)
//
#include <hip/hip_runtime.h>
#include <math.h>

#define BB 2
#define CC 272
#define GG 17
#define CG 16
#define HH 128
#define WW 128
#define HWX (HH*WW)
#define AFFC 102   // 6*G

// ---------------- Kernel W: weight re-layouts (one-off, tiny) ----------------
// dc_wt[g][c][t][oc] <- dc_w[g*16+oc][c][t];  tm_wt[ig][j][t][c] <- tm_w[ig*6+j][c][t]
__global__ __launch_bounds__(256) void wt_kernel(
    const float* __restrict__ dc_w, const float* __restrict__ tm_w,
    float* __restrict__ dc_wt, float* __restrict__ tm_wt)
{
    int i = blockIdx.x * 256 + threadIdx.x;
    if (i < GG * CG * 9 * CG) {
        int oc = i & 15, t = (i >> 4) % 9, c = (i / 144) % 16, g = i / 2304;
        dc_wt[i] = dc_w[((size_t)(g * 16 + oc) * 16 + c) * 9 + t];
    }
    if (i < GG * 6 * 9 * CG) {
        int c = i & 15, t = (i >> 4) % 9, j = (i / 144) % 6, ig = i / 864;
        tm_wt[i] = tm_w[((size_t)(ig * 6 + j) * 16 + c) * 9 + t];
    }
}

// ---------------- Kernel T: NCHW -> (B,G,HW,16) channel-last transpose ------
__global__ __launch_bounds__(256) void transpose_kernel(
    const float* __restrict__ x, float* __restrict__ xt)
{
    __shared__ float tile[CG][WW + 1];
    const int h = blockIdx.x & (HH - 1);
    const int g = (blockIdx.x >> 7) % GG;
    const int b = blockIdx.x / (GG * HH);
    const int tid = threadIdx.x;
    const float* src = x + (size_t)(b * CC + g * CG) * HWX + h * WW;
    for (int i = tid; i < CG * WW; i += 256) {
        int c = i >> 7, w = i & (WW - 1);
        tile[c][w] = src[(size_t)c * HWX + w];
    }
    __syncthreads();
    float* dst = xt + ((size_t)(b * GG + g) * HWX + h * WW) * CG;
    for (int i = tid; i < CG * WW; i += 256) {
        int w = i >> 4, c = i & 15;
        dst[i] = tile[c][w];   // i = w*16 + c : fully coalesced
    }
}

// ---------------- Kernel A: grouped 3x3 offset-transform conv ----------------
// block = (b, ig); each thread: one pixel, computes the 6 outputs of group ig
// weights read via block-uniform address -> scalar loads (SGPR broadcast)
__global__ __launch_bounds__(256) void aff_conv_kernel(
    const float* __restrict__ xt, const float* __restrict__ tm_wt,
    const float* __restrict__ tm_b, float* __restrict__ aff)
{
    const int ig = blockIdx.y;
    const int b = blockIdx.z;
    const int tid = threadIdx.x;

    const int p = blockIdx.x * 256 + tid;
    const int h = p >> 7, w = p & (WW - 1);
    const float* xb = xt + (size_t)(b * GG + ig) * HWX * CG;
    const float* wb = tm_wt + (size_t)ig * (6 * 9 * CG);   // [j][t][c]

    float acc[6];
#pragma unroll
    for (int j = 0; j < 6; ++j) acc[j] = 0.f;

#pragma unroll 1
    for (int t = 0; t < 9; ++t) {
        int hy = h + t / 3 - 1;
        int wx = w + t % 3 - 1;
        float4 xv0 = {0,0,0,0}, xv1 = {0,0,0,0}, xv2 = {0,0,0,0}, xv3 = {0,0,0,0};
        if (hy >= 0 && hy < HH && wx >= 0 && wx < WW) {
            const float4* px = (const float4*)(xb + (size_t)(hy * WW + wx) * CG);
            xv0 = px[0]; xv1 = px[1]; xv2 = px[2]; xv3 = px[3];
        }
#pragma unroll
        for (int j = 0; j < 6; ++j) {
            const float4* wp = (const float4*)(wb + (j * 9 + t) * CG); // uniform
            float4 q0 = wp[0], q1 = wp[1], q2 = wp[2], q3 = wp[3];
            float a = acc[j];
            a = fmaf(xv0.x, q0.x, a); a = fmaf(xv0.y, q0.y, a);
            a = fmaf(xv0.z, q0.z, a); a = fmaf(xv0.w, q0.w, a);
            a = fmaf(xv1.x, q1.x, a); a = fmaf(xv1.y, q1.y, a);
            a = fmaf(xv1.z, q1.z, a); a = fmaf(xv1.w, q1.w, a);
            a = fmaf(xv2.x, q2.x, a); a = fmaf(xv2.y, q2.y, a);
            a = fmaf(xv2.z, q2.z, a); a = fmaf(xv2.w, q2.w, a);
            a = fmaf(xv3.x, q3.x, a); a = fmaf(xv3.y, q3.y, a);
            a = fmaf(xv3.z, q3.z, a); a = fmaf(xv3.w, q3.w, a);
            acc[j] = a;
        }
    }
#pragma unroll
    for (int j = 0; j < 6; ++j)
        aff[(size_t)(b * AFFC + ig * 6 + j) * HWX + p] = acc[j] + tm_b[ig * 6 + j];
}

// ---------------- Kernel C: deformable grouped conv + BN-stat partials -------
// block = 16x16 pixel tile for one (b,g); each thread computes 16 out channels
// weights via block-uniform scalar loads; LDS only for the tiny reduction
__global__ __launch_bounds__(256, 8) void deform_kernel(
    const float* __restrict__ xt, const float* __restrict__ dc_wt,
    const float* __restrict__ aff_buf, float* __restrict__ pre,
    float* __restrict__ stat_sum, float* __restrict__ stat_sqs)
{
    __shared__ float red[CG][4][2];

    const int b = blockIdx.z / GG;
    const int g = blockIdx.z % GG;
    const int tid = threadIdx.y * 16 + threadIdx.x;

    const int h = blockIdx.y * 16 + threadIdx.y;
    const int w = blockIdx.x * 16 + threadIdx.x;

    // 2x3 affine params for this pixel/group; channel = 51*i + 17*j + g
    float a00 = aff_buf[(size_t)(b * AFFC + (0 * 51 + 0 * 17 + g)) * HWX + h * WW + w];
    float a01 = aff_buf[(size_t)(b * AFFC + (0 * 51 + 1 * 17 + g)) * HWX + h * WW + w];
    float a02 = aff_buf[(size_t)(b * AFFC + (0 * 51 + 2 * 17 + g)) * HWX + h * WW + w];
    float a10 = aff_buf[(size_t)(b * AFFC + (1 * 51 + 0 * 17 + g)) * HWX + h * WW + w];
    float a11 = aff_buf[(size_t)(b * AFFC + (1 * 51 + 1 * 17 + g)) * HWX + h * WW + w];
    float a12 = aff_buf[(size_t)(b * AFFC + (1 * 51 + 2 * 17 + g)) * HWX + h * WW + w];

    const float* xb = xt + (size_t)(b * GG + g) * HWX * CG;
    const float* wg = dc_wt + (size_t)g * (CG * 9 * CG);   // [c][t][oc]

    float acc[CG];
#pragma unroll
    for (int oc = 0; oc < CG; ++oc) acc[oc] = 0.f;

#pragma unroll 1
    for (int t = 0; t < 9; ++t) {
        // torch-faithful interleave: dy = flat[2t], dx = flat[2t+1], flat[e=i*9+k]
        int e0 = 2 * t, e1 = 2 * t + 1;
        int i0 = e0 / 9, k0 = e0 % 9, i1 = e1 / 9, k1 = e1 % 9;
        float ky0 = (float)(k0 / 3 - 1), kx0 = (float)(k0 % 3 - 1);
        float ky1 = (float)(k1 / 3 - 1), kx1 = (float)(k1 % 3 - 1);
        float b0y = i0 ? a10 : a00, b0x = i0 ? a11 : a01, b0c = i0 ? a12 : a02;
        float b1y = i1 ? a10 : a00, b1x = i1 ? a11 : a01, b1c = i1 ? a12 : a02;
        float dy = b0y * ky0 + b0x * kx0 + b0c;
        float dx = b1y * ky1 + b1x * kx1 + b1c;
        float py = (float)(h + t / 3 - 1) + dy;
        float px = (float)(w + t % 3 - 1) + dx;
        float y0f = floorf(py), x0f = floorf(px);
        float wy = py - y0f, wx = px - x0f;
        int y0 = (int)y0f, x0 = (int)x0f;
        int y1 = y0 + 1, x1 = x0 + 1;
        bool vy0 = (y0 >= 0) && (y0 < HH), vy1 = (y1 >= 0) && (y1 < HH);
        bool vx0 = (x0 >= 0) && (x0 < WW), vx1 = (x1 >= 0) && (x1 < WW);
        int y0c = min(max(y0, 0), HH - 1), y1c = min(max(y1, 0), HH - 1);
        int x0c = min(max(x0, 0), WW - 1), x1c = min(max(x1, 0), WW - 1);
        float w00 = (vy0 && vx0) ? (1.f - wy) * (1.f - wx) : 0.f;
        float w01 = (vy0 && vx1) ? (1.f - wy) * wx : 0.f;
        float w10 = (vy1 && vx0) ? wy * (1.f - wx) : 0.f;
        float w11 = (vy1 && vx1) ? wy * wx : 0.f;
        const float4* p00 = (const float4*)(xb + (size_t)(y0c * WW + x0c) * CG);
        const float4* p01 = (const float4*)(xb + (size_t)(y0c * WW + x1c) * CG);
        const float4* p10 = (const float4*)(xb + (size_t)(y1c * WW + x0c) * CG);
        const float4* p11 = (const float4*)(xb + (size_t)(y1c * WW + x1c) * CG);

#pragma unroll
        for (int c4 = 0; c4 < 4; ++c4) {
            float4 v00 = p00[c4], v01 = p01[c4], v10 = p10[c4], v11 = p11[c4];
            float se[4];
            se[0] = fmaf(w00, v00.x, fmaf(w01, v01.x, fmaf(w10, v10.x, w11 * v11.x)));
            se[1] = fmaf(w00, v00.y, fmaf(w01, v01.y, fmaf(w10, v10.y, w11 * v11.y)));
            se[2] = fmaf(w00, v00.z, fmaf(w01, v01.z, fmaf(w10, v10.z, w11 * v11.z)));
            se[3] = fmaf(w00, v00.w, fmaf(w01, v01.w, fmaf(w10, v10.w, w11 * v11.w)));
#pragma unroll
            for (int e = 0; e < 4; ++e) {
                float s = se[e];
                // block-uniform weight address -> scalar loads, SGPR operands
                const float4* wp = (const float4*)(wg + ((c4 * 4 + e) * 9 + t) * CG);
                float4 q0 = wp[0], q1 = wp[1], q2 = wp[2], q3 = wp[3];
                acc[0]  = fmaf(s, q0.x, acc[0]);  acc[1]  = fmaf(s, q0.y, acc[1]);
                acc[2]  = fmaf(s, q0.z, acc[2]);  acc[3]  = fmaf(s, q0.w, acc[3]);
                acc[4]  = fmaf(s, q1.x, acc[4]);  acc[5]  = fmaf(s, q1.y, acc[5]);
                acc[6]  = fmaf(s, q1.z, acc[6]);  acc[7]  = fmaf(s, q1.w, acc[7]);
                acc[8]  = fmaf(s, q2.x, acc[8]);  acc[9]  = fmaf(s, q2.y, acc[9]);
                acc[10] = fmaf(s, q2.z, acc[10]); acc[11] = fmaf(s, q2.w, acc[11]);
                acc[12] = fmaf(s, q3.x, acc[12]); acc[13] = fmaf(s, q3.y, acc[13]);
                acc[14] = fmaf(s, q3.z, acc[14]); acc[15] = fmaf(s, q3.w, acc[15]);
            }
        }
    }

    // write pre-BN output + block-level BN partial sums
    const int lane = tid & 63, wave = tid >> 6;
#pragma unroll
    for (int oc = 0; oc < CG; ++oc) {
        pre[(size_t)(b * CC + g * CG + oc) * HWX + h * WW + w] = acc[oc];
    }
#pragma unroll 1
    for (int oc = 0; oc < CG; ++oc) {
        float s = acc[oc], q = acc[oc] * acc[oc];
#pragma unroll
        for (int off = 32; off > 0; off >>= 1) {
            s += __shfl_down(s, off);
            q += __shfl_down(q, off);
        }
        if (lane == 0) { red[oc][wave][0] = s; red[oc][wave][1] = q; }
    }
    __syncthreads();
    if (tid < CG) {
        float s = red[tid][0][0] + red[tid][1][0] + red[tid][2][0] + red[tid][3][0];
        float q = red[tid][0][1] + red[tid][1][1] + red[tid][2][1] + red[tid][3][1];
        int ch = g * CG + tid;
        atomicAdd(&stat_sum[ch], s);
        atomicAdd(&stat_sqs[ch], q);
    }
}

// ---------------- Kernel D: BN (training stats) + residual ReLU (in-place) ---
__global__ __launch_bounds__(256) void bn_res_relu_kernel(
    const float* __restrict__ x,
    const float* __restrict__ stat_sum, const float* __restrict__ stat_sqs,
    const float* __restrict__ gamma, const float* __restrict__ beta,
    float* __restrict__ out)
{
    int idx = blockIdx.x * 256 + threadIdx.x;
    int c = (idx >> 14) % CC;
    const float n = (float)(BB * HWX);
    float mean = stat_sum[c] / n;
    float var = stat_sqs[c] / n - mean * mean;
    float inv = rsqrtf(var + 1e-5f);
    float v = (out[idx] - mean) * inv * gamma[c] + beta[c] + x[idx];
    out[idx] = fmaxf(v, 0.f);
}

extern "C" void kernel_launch(void* const* d_in, const int* in_sizes, int n_in,
                              void* d_out, int out_size, void* d_ws, size_t ws_size,
                              hipStream_t stream)
{
    const float* x     = (const float*)d_in[0];
    const float* tm_w  = (const float*)d_in[1];
    const float* tm_b  = (const float*)d_in[2];
    const float* dc_w  = (const float*)d_in[3];
    const float* gamma = (const float*)d_in[4];
    const float* beta  = (const float*)d_in[5];
    float* out = (float*)d_out;

    float* ws = (float*)d_ws;
    float* stat_sum = ws;                         // 272 floats
    float* stat_sqs = ws + CC;                    // 272 floats
    float* dc_wt = ws + 1024;                     // 39168 floats
    float* tm_wt = dc_wt + 39424;                 // 14688 floats
    float* aff = tm_wt + 14848;                   // B*102*HW floats
    float* xt  = aff + (size_t)BB * AFFC * HWX;   // B*G*HW*16 floats

    hipMemsetAsync(stat_sum, 0, 2 * CC * sizeof(float), stream);

    wt_kernel<<<dim3(153), dim3(256), 0, stream>>>(dc_w, tm_w, dc_wt, tm_wt);
    transpose_kernel<<<dim3(BB * GG * HH), dim3(256), 0, stream>>>(x, xt);
    aff_conv_kernel<<<dim3(HWX / 256, GG, BB), dim3(256), 0, stream>>>(xt, tm_wt, tm_b, aff);
    deform_kernel<<<dim3(WW / 16, HH / 16, BB * GG), dim3(16, 16), 0, stream>>>(
        xt, dc_wt, aff, out /*pre*/, stat_sum, stat_sqs);
    bn_res_relu_kernel<<<dim3(BB * CC * HWX / 256), dim3(256), 0, stream>>>(
        x, stat_sum, stat_sqs, gamma, beta, out);
}

// Round 5
// 180.777 us; speedup vs baseline: 1.6294x; 1.6294x over previous
//
#include <hip/hip_runtime.h>
#include <math.h>

#define BB 2
#define CC 272
#define GG 17
#define CG 16
#define HH 128
#define WW 128
#define HWX (HH*WW)
#define AFFC 102   // 6*G
#define NSLAB (BB*GG)          // 34
#define TILES_PER_SLAB 64      // (128/16)^2
#define NWG (NSLAB*TILES_PER_SLAB)  // 2176 = 8*272
#define WGPX (NWG/8)           // 272 per XCD

// ---------------- Kernel W: weight re-layouts (one-off, tiny) ----------------
// dc_wt[g][c][t][oc] <- dc_w[g*16+oc][c][t];  tm_wt[ig][j][t][c] <- tm_w[ig*6+j][c][t]
__global__ __launch_bounds__(256) void wt_kernel(
    const float* __restrict__ dc_w, const float* __restrict__ tm_w,
    float* __restrict__ dc_wt, float* __restrict__ tm_wt)
{
    int i = blockIdx.x * 256 + threadIdx.x;
    if (i < GG * CG * 9 * CG) {
        int oc = i & 15, t = (i >> 4) % 9, c = (i / 144) % 16, g = i / 2304;
        dc_wt[i] = dc_w[((size_t)(g * 16 + oc) * 16 + c) * 9 + t];
    }
    if (i < GG * 6 * 9 * CG) {
        int c = i & 15, t = (i >> 4) % 9, j = (i / 144) % 6, ig = i / 864;
        tm_wt[i] = tm_w[((size_t)(ig * 6 + j) * 16 + c) * 9 + t];
    }
}

// ---------------- Kernel T: NCHW -> (B,G,HW,16) channel-last transpose ------
__global__ __launch_bounds__(256) void transpose_kernel(
    const float* __restrict__ x, float* __restrict__ xt)
{
    __shared__ float tile[CG][WW + 1];
    const int h = blockIdx.x & (HH - 1);
    const int g = (blockIdx.x >> 7) % GG;
    const int b = blockIdx.x / (GG * HH);
    const int tid = threadIdx.x;
    const float* src = x + (size_t)(b * CC + g * CG) * HWX + h * WW;
    for (int i = tid; i < CG * WW; i += 256) {
        int c = i >> 7, w = i & (WW - 1);
        tile[c][w] = src[(size_t)c * HWX + w];
    }
    __syncthreads();
    float* dst = xt + ((size_t)(b * GG + g) * HWX + h * WW) * CG;
    for (int i = tid; i < CG * WW; i += 256) {
        int w = i >> 4, c = i & 15;
        dst[i] = tile[c][w];   // i = w*16 + c : fully coalesced
    }
}

// ---------------- Kernel A: grouped 3x3 offset-transform conv ----------------
// block = (b, ig); each thread: one pixel, computes the 6 outputs of group ig
// weights read via block-uniform address -> scalar loads (SGPR broadcast)
__global__ __launch_bounds__(256) void aff_conv_kernel(
    const float* __restrict__ xt, const float* __restrict__ tm_wt,
    const float* __restrict__ tm_b, float* __restrict__ aff)
{
    const int ig = blockIdx.y;
    const int b = blockIdx.z;
    const int tid = threadIdx.x;

    const int p = blockIdx.x * 256 + tid;
    const int h = p >> 7, w = p & (WW - 1);
    const float* xb = xt + (size_t)(b * GG + ig) * HWX * CG;
    const float* wb = tm_wt + (size_t)ig * (6 * 9 * CG);   // [j][t][c]

    float acc[6];
#pragma unroll
    for (int j = 0; j < 6; ++j) acc[j] = 0.f;

#pragma unroll 1
    for (int t = 0; t < 9; ++t) {
        int hy = h + t / 3 - 1;
        int wx = w + t % 3 - 1;
        float4 xv0 = {0,0,0,0}, xv1 = {0,0,0,0}, xv2 = {0,0,0,0}, xv3 = {0,0,0,0};
        if (hy >= 0 && hy < HH && wx >= 0 && wx < WW) {
            const float4* px = (const float4*)(xb + (size_t)(hy * WW + wx) * CG);
            xv0 = px[0]; xv1 = px[1]; xv2 = px[2]; xv3 = px[3];
        }
#pragma unroll
        for (int j = 0; j < 6; ++j) {
            const float4* wp = (const float4*)(wb + (j * 9 + t) * CG); // uniform
            float4 q0 = wp[0], q1 = wp[1], q2 = wp[2], q3 = wp[3];
            float a = acc[j];
            a = fmaf(xv0.x, q0.x, a); a = fmaf(xv0.y, q0.y, a);
            a = fmaf(xv0.z, q0.z, a); a = fmaf(xv0.w, q0.w, a);
            a = fmaf(xv1.x, q1.x, a); a = fmaf(xv1.y, q1.y, a);
            a = fmaf(xv1.z, q1.z, a); a = fmaf(xv1.w, q1.w, a);
            a = fmaf(xv2.x, q2.x, a); a = fmaf(xv2.y, q2.y, a);
            a = fmaf(xv2.z, q2.z, a); a = fmaf(xv2.w, q2.w, a);
            a = fmaf(xv3.x, q3.x, a); a = fmaf(xv3.y, q3.y, a);
            a = fmaf(xv3.z, q3.z, a); a = fmaf(xv3.w, q3.w, a);
            acc[j] = a;
        }
    }
#pragma unroll
    for (int j = 0; j < 6; ++j)
        aff[(size_t)(b * AFFC + ig * 6 + j) * HWX + p] = acc[j] + tm_b[ig * 6 + j];
}

// ---------------- Kernel C: deformable grouped conv + BN-stat partials -------
// 1D grid, XCD-chunked: each XCD L2 serves a contiguous ~4.25-slab window of xt
__global__ __launch_bounds__(256, 4) void deform_kernel(
    const float* __restrict__ xt, const float* __restrict__ dc_wt,
    const float* __restrict__ aff_buf, float* __restrict__ pre,
    float* __restrict__ stat_sum, float* __restrict__ stat_sqs)
{
    __shared__ float red[CG][4][2];

    // XCD-aware remap: blockIdx.x%8 = XCD (dispatch round-robin); give each
    // XCD a contiguous range of (slab,tile) work items.
    const int bid = blockIdx.x;
    const int work = (bid & 7) * WGPX + (bid >> 3);
    const int slab = work / TILES_PER_SLAB;      // (b,g)
    const int tile = work % TILES_PER_SLAB;
    const int b = slab / GG;
    const int g = slab % GG;

    const int tid = threadIdx.y * 16 + threadIdx.x;
    const int h = (tile >> 3) * 16 + threadIdx.y;
    const int w = (tile & 7) * 16 + threadIdx.x;

    // 2x3 affine params for this pixel/group; channel = 51*i + 17*j + g
    float a00 = aff_buf[(size_t)(b * AFFC + (0 * 51 + 0 * 17 + g)) * HWX + h * WW + w];
    float a01 = aff_buf[(size_t)(b * AFFC + (0 * 51 + 1 * 17 + g)) * HWX + h * WW + w];
    float a02 = aff_buf[(size_t)(b * AFFC + (0 * 51 + 2 * 17 + g)) * HWX + h * WW + w];
    float a10 = aff_buf[(size_t)(b * AFFC + (1 * 51 + 0 * 17 + g)) * HWX + h * WW + w];
    float a11 = aff_buf[(size_t)(b * AFFC + (1 * 51 + 1 * 17 + g)) * HWX + h * WW + w];
    float a12 = aff_buf[(size_t)(b * AFFC + (1 * 51 + 2 * 17 + g)) * HWX + h * WW + w];

    const float* xb = xt + (size_t)(b * GG + g) * HWX * CG;
    const float* wg = dc_wt + (size_t)g * (CG * 9 * CG);   // [c][t][oc]

    float acc[CG];
#pragma unroll
    for (int oc = 0; oc < CG; ++oc) acc[oc] = 0.f;

#pragma unroll 1
    for (int t = 0; t < 9; ++t) {
        // torch-faithful interleave: dy = flat[2t], dx = flat[2t+1], flat[e=i*9+k]
        int e0 = 2 * t, e1 = 2 * t + 1;
        int i0 = e0 / 9, k0 = e0 % 9, i1 = e1 / 9, k1 = e1 % 9;
        float ky0 = (float)(k0 / 3 - 1), kx0 = (float)(k0 % 3 - 1);
        float ky1 = (float)(k1 / 3 - 1), kx1 = (float)(k1 % 3 - 1);
        float b0y = i0 ? a10 : a00, b0x = i0 ? a11 : a01, b0c = i0 ? a12 : a02;
        float b1y = i1 ? a10 : a00, b1x = i1 ? a11 : a01, b1c = i1 ? a12 : a02;
        float dy = b0y * ky0 + b0x * kx0 + b0c;
        float dx = b1y * ky1 + b1x * kx1 + b1c;
        float py = (float)(h + t / 3 - 1) + dy;
        float px = (float)(w + t % 3 - 1) + dx;
        float y0f = floorf(py), x0f = floorf(px);
        float wy = py - y0f, wx = px - x0f;
        int y0 = (int)y0f, x0 = (int)x0f;
        int y1 = y0 + 1, x1 = x0 + 1;
        bool vy0 = (y0 >= 0) && (y0 < HH), vy1 = (y1 >= 0) && (y1 < HH);
        bool vx0 = (x0 >= 0) && (x0 < WW), vx1 = (x1 >= 0) && (x1 < WW);
        int y0c = min(max(y0, 0), HH - 1), y1c = min(max(y1, 0), HH - 1);
        int x0c = min(max(x0, 0), WW - 1), x1c = min(max(x1, 0), WW - 1);
        float w00 = (vy0 && vx0) ? (1.f - wy) * (1.f - wx) : 0.f;
        float w01 = (vy0 && vx1) ? (1.f - wy) * wx : 0.f;
        float w10 = (vy1 && vx0) ? wy * (1.f - wx) : 0.f;
        float w11 = (vy1 && vx1) ? wy * wx : 0.f;
        const float4* p00 = (const float4*)(xb + (size_t)(y0c * WW + x0c) * CG);
        const float4* p01 = (const float4*)(xb + (size_t)(y0c * WW + x1c) * CG);
        const float4* p10 = (const float4*)(xb + (size_t)(y1c * WW + x0c) * CG);
        const float4* p11 = (const float4*)(xb + (size_t)(y1c * WW + x1c) * CG);

#pragma unroll
        for (int c4 = 0; c4 < 4; ++c4) {
            float4 v00 = p00[c4], v01 = p01[c4], v10 = p10[c4], v11 = p11[c4];
            float se[4];
            se[0] = fmaf(w00, v00.x, fmaf(w01, v01.x, fmaf(w10, v10.x, w11 * v11.x)));
            se[1] = fmaf(w00, v00.y, fmaf(w01, v01.y, fmaf(w10, v10.y, w11 * v11.y)));
            se[2] = fmaf(w00, v00.z, fmaf(w01, v01.z, fmaf(w10, v10.z, w11 * v11.z)));
            se[3] = fmaf(w00, v00.w, fmaf(w01, v01.w, fmaf(w10, v10.w, w11 * v11.w)));
#pragma unroll
            for (int e = 0; e < 4; ++e) {
                float s = se[e];
                // block-uniform weight address -> scalar loads, SGPR operands
                const float4* wp = (const float4*)(wg + ((c4 * 4 + e) * 9 + t) * CG);
                float4 q0 = wp[0], q1 = wp[1], q2 = wp[2], q3 = wp[3];
                acc[0]  = fmaf(s, q0.x, acc[0]);  acc[1]  = fmaf(s, q0.y, acc[1]);
                acc[2]  = fmaf(s, q0.z, acc[2]);  acc[3]  = fmaf(s, q0.w, acc[3]);
                acc[4]  = fmaf(s, q1.x, acc[4]);  acc[5]  = fmaf(s, q1.y, acc[5]);
                acc[6]  = fmaf(s, q1.z, acc[6]);  acc[7]  = fmaf(s, q1.w, acc[7]);
                acc[8]  = fmaf(s, q2.x, acc[8]);  acc[9]  = fmaf(s, q2.y, acc[9]);
                acc[10] = fmaf(s, q2.z, acc[10]); acc[11] = fmaf(s, q2.w, acc[11]);
                acc[12] = fmaf(s, q3.x, acc[12]); acc[13] = fmaf(s, q3.y, acc[13]);
                acc[14] = fmaf(s, q3.z, acc[14]); acc[15] = fmaf(s, q3.w, acc[15]);
            }
        }
    }

    // write pre-BN output + block-level BN partial sums
    const int lane = tid & 63, wave = tid >> 6;
#pragma unroll
    for (int oc = 0; oc < CG; ++oc) {
        pre[(size_t)(b * CC + g * CG + oc) * HWX + h * WW + w] = acc[oc];
    }
#pragma unroll 1
    for (int oc = 0; oc < CG; ++oc) {
        float s = acc[oc], q = acc[oc] * acc[oc];
#pragma unroll
        for (int off = 32; off > 0; off >>= 1) {
            s += __shfl_down(s, off);
            q += __shfl_down(q, off);
        }
        if (lane == 0) { red[oc][wave][0] = s; red[oc][wave][1] = q; }
    }
    __syncthreads();
    if (tid < CG) {
        float s = red[tid][0][0] + red[tid][1][0] + red[tid][2][0] + red[tid][3][0];
        float q = red[tid][0][1] + red[tid][1][1] + red[tid][2][1] + red[tid][3][1];
        int ch = g * CG + tid;
        atomicAdd(&stat_sum[ch], s);
        atomicAdd(&stat_sqs[ch], q);
    }
}

// ---------------- Kernel D: BN (training stats) + residual ReLU (in-place) ---
__global__ __launch_bounds__(256) void bn_res_relu_kernel(
    const float* __restrict__ x,
    const float* __restrict__ stat_sum, const float* __restrict__ stat_sqs,
    const float* __restrict__ gamma, const float* __restrict__ beta,
    float* __restrict__ out)
{
    int idx = blockIdx.x * 256 + threadIdx.x;
    int c = (idx >> 14) % CC;
    const float n = (float)(BB * HWX);
    float mean = stat_sum[c] / n;
    float var = stat_sqs[c] / n - mean * mean;
    float inv = rsqrtf(var + 1e-5f);
    float v = (out[idx] - mean) * inv * gamma[c] + beta[c] + x[idx];
    out[idx] = fmaxf(v, 0.f);
}

extern "C" void kernel_launch(void* const* d_in, const int* in_sizes, int n_in,
                              void* d_out, int out_size, void* d_ws, size_t ws_size,
                              hipStream_t stream)
{
    const float* x     = (const float*)d_in[0];
    const float* tm_w  = (const float*)d_in[1];
    const float* tm_b  = (const float*)d_in[2];
    const float* dc_w  = (const float*)d_in[3];
    const float* gamma = (const float*)d_in[4];
    const float* beta  = (const float*)d_in[5];
    float* out = (float*)d_out;

    float* ws = (float*)d_ws;
    float* stat_sum = ws;                         // 272 floats
    float* stat_sqs = ws + CC;                    // 272 floats
    float* dc_wt = ws + 1024;                     // 39168 floats
    float* tm_wt = dc_wt + 39424;                 // 14688 floats
    float* aff = tm_wt + 14848;                   // B*102*HW floats
    float* xt  = aff + (size_t)BB * AFFC * HWX;   // B*G*HW*16 floats

    hipMemsetAsync(stat_sum, 0, 2 * CC * sizeof(float), stream);

    wt_kernel<<<dim3(153), dim3(256), 0, stream>>>(dc_w, tm_w, dc_wt, tm_wt);
    transpose_kernel<<<dim3(BB * GG * HH), dim3(256), 0, stream>>>(x, xt);
    aff_conv_kernel<<<dim3(HWX / 256, GG, BB), dim3(256), 0, stream>>>(xt, tm_wt, tm_b, aff);
    deform_kernel<<<dim3(NWG), dim3(16, 16), 0, stream>>>(
        xt, dc_wt, aff, out /*pre*/, stat_sum, stat_sqs);
    bn_res_relu_kernel<<<dim3(BB * CC * HWX / 256), dim3(256), 0, stream>>>(
        x, stat_sum, stat_sqs, gamma, beta, out);
}